// Round 6
// baseline (97.634 us; speedup 1.0000x reference)
//
#include <hip/hip_runtime.h>
#include <math.h>

// B=16, C=128, N=1024, HEADS=4, DIM_HEAD=32. qkv rows = 384 (q:0-127, k:128-255, v:256-383).
#define CIN 128
#define NTOK 1024
#define SCALE_Q 0.17677669529663687f /* 32^-0.5 */
#define GN_EPS 1e-5f
#define PB (CIN * NTOK) /* 131072 */

// ---- workspace layout (float units), all plain stores (no init needed) ----
#define WS_WQKVB 0        /* bf16 [256][128] q,k weights   (16384 fl) */
#define WS_WVT   16384    /* bf16 [128][128] wvT[k][c']    (8192 fl)  */
#define WS_PSTATS 24576   /* f32  [256][2]                 (512 fl)   */
#define WS_PQSUM 25088    /* f32  [256][128]               (32768 fl) */
#define WS_PMT   57856    /* f32  [256][4][32][32] pMT[c][c'] (1048576 fl) */
#define WS_WEFF  1106432  /* bf16 [16][128][128]           (131072 fl) */
#define WS_BIAS  1237504  /* f32  [16][128]                (2048 fl)  */

typedef __bf16 bf16x8 __attribute__((ext_vector_type(8)));
typedef float f32x4 __attribute__((ext_vector_type(4)));

__device__ __forceinline__ unsigned short f2bf(float f) {
    union { float f; unsigned u; } v; v.f = f;
    unsigned r = v.u + 0x7fffu + ((v.u >> 16) & 1u);
    return (unsigned short)(r >> 16);
}
__device__ __forceinline__ unsigned pack2(float a, float b) {
    return (unsigned)f2bf(a) | ((unsigned)f2bf(b) << 16);
}

// ---------------------------------------------------------------------------
// K1: per-32KB-chunk stats partials; wqkv q/k rows -> bf16; v rows -> wvT bf16.
__global__ __launch_bounds__(256) void k_pre(const float* __restrict__ x,
                                             const float* __restrict__ wqkv,
                                             float* __restrict__ ws) {
    float* pstats = ws + WS_PSTATS;
    unsigned short* wqkvb = (unsigned short*)(ws + WS_WQKVB);
    unsigned short* wvT = (unsigned short*)(ws + WS_WVT);
    __shared__ float sD[8];
    int bid = blockIdx.x, t = threadIdx.x;
    int lane = t & 63, wave = t >> 6;
    const float4* p = (const float4*)(x + (size_t)bid * 8192);
    float s = 0.f, s2 = 0.f;
    #pragma unroll
    for (int i = 0; i < 8; i++) {
        float4 v = p[t + 256 * i];
        s += v.x + v.y + v.z + v.w;
        s2 += v.x * v.x + v.y * v.y + v.z * v.z + v.w * v.w;
    }
    #pragma unroll
    for (int off = 32; off; off >>= 1) {
        s += __shfl_down(s, off);
        s2 += __shfl_down(s2, off);
    }
    if (lane == 0) { sD[wave * 2] = s; sD[wave * 2 + 1] = s2; }
    if (bid < 32) {                 // q,k weight rows -> bf16 (row-major)
        float4 v = ((const float4*)(wqkv + bid * 1024))[t];
        uint2 pk2; pk2.x = pack2(v.x, v.y); pk2.y = pack2(v.z, v.w);
        *(uint2*)(wqkvb + bid * 1024 + t * 4) = pk2;
    } else if (bid < 48) {          // v rows, transposed: wvT[k][c'] = wqkv[256+c'][k]
        int g = bid - 32;
        int kk = g * 8 + (t >> 5), cq = t & 31;
        float v0 = wqkv[(256 + cq * 4 + 0) * 128 + kk];
        float v1 = wqkv[(256 + cq * 4 + 1) * 128 + kk];
        float v2 = wqkv[(256 + cq * 4 + 2) * 128 + kk];
        float v3 = wqkv[(256 + cq * 4 + 3) * 128 + kk];
        uint2 pk2; pk2.x = pack2(v0, v1); pk2.y = pack2(v2, v3);
        *(uint2*)(wvT + kk * 128 + cq * 4) = pk2;
    }
    __syncthreads();
    if (t == 0) {
        pstats[bid * 2] = sD[0] + sD[2] + sD[4] + sD[6];
        pstats[bid * 2 + 1] = sD[1] + sD[3] + sD[5] + sD[7];
    }
}

// ---------------------------------------------------------------------------
// K2: per (b, 64-token tile), 512 thr. GN->Al; q,k MFMA; exp + k-softmax;
// qsum partials; pMT[c][c'] partials (MFMA). No V work.
// LDS: Al[64][136]us@0 | Xl f32[128][68] @17408 (aliased by kTl[128][68]@17408,
//      qTl[128][68]@34816) | Bl[256][136]us@52224 | sD f32[256]@121856.
__global__ __launch_bounds__(512, 1) void k_qk(const float* __restrict__ x,
                                               const float* __restrict__ gw,
                                               const float* __restrict__ gb,
                                               float* __restrict__ ws) {
    __shared__ __align__(16) char smem[122880];
    unsigned short (*Al)[136] = (unsigned short(*)[136])smem;
    float (*Xl)[68] = (float(*)[68])(smem + 17408);
    unsigned short (*kTl)[68] = (unsigned short(*)[68])(smem + 17408);
    unsigned short (*qTl)[68] = (unsigned short(*)[68])(smem + 34816);
    unsigned short (*Bl)[136] = (unsigned short(*)[136])(smem + 52224);
    float* sD = (float*)(smem + 121856);

    unsigned short* wqkvb = (unsigned short*)(ws + WS_WQKVB);
    float* pstats = ws + WS_PSTATS;
    float* pqsum = ws + WS_PQSUM;
    float* pMT = ws + WS_PMT;

    int bid = blockIdx.x, t = threadIdx.x;
    int b = bid >> 4, nt = bid & 15;
    int lane = t & 63, wave = t >> 6;
    int l15 = lane & 15, lk = (lane >> 4) * 8;
    int sel = wave >> 1;            // 0..3 (q rows: 0,1; k rows: 2,3)
    int wn0 = (wave & 1) * 32;      // token half

    // ---- P1: pstats -> sD; x -> regs; q/k weights -> Bl ----
    if (t < 32) sD[t] = pstats[b * 32 + t];
    int cx = t >> 2, qtr = t & 3;
    const float4* xsrc = (const float4*)(x + ((size_t)b * CIN + cx) * NTOK + nt * 64 + qtr * 16);
    float4 xr0 = xsrc[0], xr1 = xsrc[1], xr2 = xsrc[2], xr3 = xsrc[3];
    {
        int row = t >> 1, hf = t & 1;
        const uint4* src = (const uint4*)(wqkvb + (size_t)row * CIN + hf * 64);
        uint4* dst = (uint4*)&Bl[row][hf * 64];
        #pragma unroll
        for (int j = 0; j < 8; j++) dst[j] = src[j];
    }
    __syncthreads();
    // ---- P2: mu/rs; GN'd store to Xl ----
    float mu, rsv;
    {
        float s = 0.f, s2 = 0.f;
        #pragma unroll
        for (int i = 0; i < 16; i++) { s += sD[2 * i]; s2 += sD[2 * i + 1]; }
        mu = s * (1.f / PB);
        float var = s2 * (1.f / PB) - mu * mu;
        rsv = rsqrtf(var + GN_EPS);
    }
    {
        float g = gw[cx] * rsv, bb = gb[cx] - mu * g;
        float4 r0 = { xr0.x * g + bb, xr0.y * g + bb, xr0.z * g + bb, xr0.w * g + bb };
        float4 r1 = { xr1.x * g + bb, xr1.y * g + bb, xr1.z * g + bb, xr1.w * g + bb };
        float4 r2 = { xr2.x * g + bb, xr2.y * g + bb, xr2.z * g + bb, xr2.w * g + bb };
        float4 r3 = { xr3.x * g + bb, xr3.y * g + bb, xr3.z * g + bb, xr3.w * g + bb };
        *(float4*)&Xl[cx][qtr * 16 + 0] = r0;
        *(float4*)&Xl[cx][qtr * 16 + 4] = r1;
        *(float4*)&Xl[cx][qtr * 16 + 8] = r2;
        *(float4*)&Xl[cx][qtr * 16 + 12] = r3;
    }
    __syncthreads();
    // ---- P3: transpose + bf16 -> Al[n][c] ----
    {
        int n = t & 63, kq = (t >> 6) * 16;
        unsigned pk[8];
        #pragma unroll
        for (int j = 0; j < 8; j++) pk[j] = pack2(Xl[kq + 2 * j][n], Xl[kq + 2 * j + 1][n]);
        *(uint4*)&Al[n][kq] = *(uint4*)pk;
        *(uint4*)(&Al[n][kq] + 8) = *(uint4*)(pk + 4);
    }
    __syncthreads();
    // ---- P4: q/k MFMA; exp; k-softmax; transposed stores; qsum partials ----
    f32x4 acc[2][4] = {};
    #pragma unroll
    for (int ks = 0; ks < 4; ks++) {
        bf16x8 av[2], bv[4];
        #pragma unroll
        for (int i = 0; i < 2; i++) av[i] = *(const bf16x8*)&Al[wn0 + i * 16 + l15][ks * 32 + lk];
        #pragma unroll
        for (int j = 0; j < 4; j++) bv[j] = *(const bf16x8*)&Bl[sel * 64 + j * 16 + l15][ks * 32 + lk];
        #pragma unroll
        for (int i = 0; i < 2; i++)
            #pragma unroll
            for (int j = 0; j < 4; j++)
                acc[i][j] = __builtin_amdgcn_mfma_f32_16x16x32_bf16(av[i], bv[j], acc[i][j], 0, 0, 0);
    }
    float e[2][4][4];
    #pragma unroll
    for (int i = 0; i < 2; i++)
        #pragma unroll
        for (int j = 0; j < 4; j++)
            #pragma unroll
            for (int r = 0; r < 4; r++) e[i][j][r] = __expf(acc[i][j][r]);

    if (sel >= 2) {   // k rows: softmax over each head's 32 channels
        #pragma unroll
        for (int i = 0; i < 2; i++)
            #pragma unroll
            for (int r = 0; r < 4; r++) {
                float e01 = e[i][0][r] + e[i][1][r];
                float e23 = e[i][2][r] + e[i][3][r];
                #pragma unroll
                for (int m = 1; m < 16; m <<= 1) {
                    e01 += __shfl_xor(e01, m);
                    e23 += __shfl_xor(e23, m);
                }
                float i01 = 1.f / e01, i23 = 1.f / e23;
                e[i][0][r] *= i01; e[i][1][r] *= i01;
                e[i][2][r] *= i23; e[i][3][r] *= i23;
            }
        #pragma unroll
        for (int i = 0; i < 2; i++)
            #pragma unroll
            for (int j = 0; j < 4; j++) {
                int ch = (sel - 2) * 64 + j * 16 + l15;
                int tokb = wn0 + i * 16 + (lane >> 4) * 4;
                *(unsigned*)&kTl[ch][tokb] = pack2(e[i][j][0], e[i][j][1]);
                *(unsigned*)&kTl[ch][tokb + 2] = pack2(e[i][j][2], e[i][j][3]);
            }
    } else {          // q rows: transposed e^q store + per-channel partial sums
        #pragma unroll
        for (int i = 0; i < 2; i++)
            #pragma unroll
            for (int j = 0; j < 4; j++) {
                int ch = sel * 64 + j * 16 + l15;
                int tokb = wn0 + i * 16 + (lane >> 4) * 4;
                *(unsigned*)&qTl[ch][tokb] = pack2(e[i][j][0], e[i][j][1]);
                *(unsigned*)&qTl[ch][tokb + 2] = pack2(e[i][j][2], e[i][j][3]);
            }
        #pragma unroll
        for (int j = 0; j < 4; j++) {
            float sq = 0.f;
            #pragma unroll
            for (int i = 0; i < 2; i++)
                #pragma unroll
                for (int r = 0; r < 4; r++) sq += e[i][j][r];
            sq += __shfl_xor(sq, 16);
            sq += __shfl_xor(sq, 32);
            if (lane < 16) sD[(wave & 1) * 128 + sel * 64 + j * 16 + lane] = sq;
        }
    }
    __syncthreads();
    // ---- P5: pqsum store + pMT partial (MFMA, waves 0-3 = heads) ----
    if (t < 128) pqsum[(size_t)bid * 128 + t] = sD[t] + sD[128 + t];
    if (wave < 4) {
        int h = wave;
        f32x4 mac[2][2] = {};
        #pragma unroll
        for (int ks = 0; ks < 2; ks++) {
            bf16x8 av[2], bv[2];
            #pragma unroll
            for (int i = 0; i < 2; i++) av[i] = *(const bf16x8*)&qTl[h * 32 + i * 16 + l15][ks * 32 + lk];
            #pragma unroll
            for (int j = 0; j < 2; j++) bv[j] = *(const bf16x8*)&kTl[h * 32 + j * 16 + l15][ks * 32 + lk];
            #pragma unroll
            for (int i = 0; i < 2; i++)
                #pragma unroll
                for (int j = 0; j < 2; j++)
                    mac[i][j] = __builtin_amdgcn_mfma_f32_16x16x32_bf16(av[i], bv[j], mac[i][j], 0, 0, 0);
        }
        // D[c][c'] = sum_n e^q[n][c] * k_sm[n][c']  -> pMT[bid][h][c][c']
        float* pmb = pMT + ((size_t)bid * 4 + h) * 1024;
        #pragma unroll
        for (int i = 0; i < 2; i++)
            #pragma unroll
            for (int j = 0; j < 2; j++)
                #pragma unroll
                for (int r = 0; r < 4; r++)
                    pmb[(i * 16 + (lane >> 4) * 4 + r) * 32 + j * 16 + l15] = mac[i][j][r];
    }
}

// ---------------------------------------------------------------------------
// K3: one block per batch (16 x 512). Reduce partials; Weff' = wout*qinv
// (x) M (x) Wv, GN-folded; bias'. Two MFMA chains, all operands K-contiguous.
// LDS: pMTb us[4][32][40]@0 | wvTb us[128][136]@10240 (aliased by WeffL) |
//      woutb us[128][136]@45056 | B2T us[128][136]@79872 | sD f32[512]@114688
__global__ __launch_bounds__(512, 1) void k_weff(const float* __restrict__ gw,
                                                 const float* __restrict__ gb,
                                                 const float* __restrict__ wout,
                                                 const float* __restrict__ bout,
                                                 float* __restrict__ ws) {
    __shared__ __align__(16) char smem[116736];
    unsigned short (*pMTb)[32][40] = (unsigned short(*)[32][40])smem;
    unsigned short (*wvTb)[136] = (unsigned short(*)[136])(smem + 10240);
    unsigned short (*WeffL)[136] = (unsigned short(*)[136])(smem + 10240);
    unsigned short (*woutb)[136] = (unsigned short(*)[136])(smem + 45056);
    unsigned short (*B2T)[136] = (unsigned short(*)[136])(smem + 79872);
    float* sD = (float*)(smem + 114688);   // [0:128) qinv | [128:256) gscale | [256:384) bb | [384:416) stats

    float* pstats = ws + WS_PSTATS;
    float* pqsum = ws + WS_PQSUM;
    float* pMT = ws + WS_PMT;
    unsigned short* wvT = (unsigned short*)(ws + WS_WVT);
    unsigned short* weffg = (unsigned short*)(ws + WS_WEFF);
    float* biasg = ws + WS_BIAS;

    int b = blockIdx.x, t = threadIdx.x;
    int lane = t & 63, wave = t >> 6;
    int l15 = lane & 15, lk = (lane >> 4) * 8;

    // ---- P1: reductions + staging ----
    if (t < 32) sD[384 + t] = pstats[b * 32 + t];
    if (t < 128) {
        float s = 0.f;
        #pragma unroll
        for (int i = 0; i < 16; i++) s += pqsum[(size_t)(b * 16 + i) * 128 + t];
        sD[t] = SCALE_Q / s;
    }
    #pragma unroll
    for (int s2 = 0; s2 < 2; s2++) {   // reduce pMT (16 tiles) -> pMTb bf16
        int f4 = t * 2 + s2;           // 0..1023 float4-slots
        int h = f4 >> 8, c = (f4 >> 3) & 31, cp0 = (f4 & 7) * 4;
        float4 m = { 0.f, 0.f, 0.f, 0.f };
        for (int i = 0; i < 16; i++) {
            float4 v = *(const float4*)&pMT[(((size_t)(b * 16 + i)) * 4 + h) * 1024 + c * 32 + cp0];
            m.x += v.x; m.y += v.y; m.z += v.z; m.w += v.w;
        }
        uint2 u; u.x = pack2(m.x, m.y); u.y = pack2(m.z, m.w);
        *(uint2*)&pMTb[h][c][cp0] = u;
    }
    {   // stage wvT -> LDS
        int row = t >> 2, q4 = t & 3;
        const uint4* src = (const uint4*)(wvT + row * 128) + q4 * 4;
        #pragma unroll
        for (int m = 0; m < 4; m++) *(uint4*)&wvTb[row][q4 * 32 + m * 8] = src[m];
    }
    {   // stage wout fp32 -> bf16 LDS
        int row = t >> 2, q4 = t & 3;
        const float4* src = (const float4*)(wout + row * 128 + q4 * 32);
        #pragma unroll
        for (int i = 0; i < 8; i++) {
            float4 v = src[i];
            uint2 u; u.x = pack2(v.x, v.y); u.y = pack2(v.z, v.w);
            *(uint2*)&woutb[row][q4 * 32 + i * 4] = u;
        }
    }
    __syncthreads();
    // ---- P1.5: gscale / bb from stats ----
    if (t < 128) {
        float s = 0.f, s2 = 0.f;
        #pragma unroll
        for (int i = 0; i < 16; i++) { s += sD[384 + 2 * i]; s2 += sD[384 + 2 * i + 1]; }
        float mu = s * (1.f / PB);
        float var = s2 * (1.f / PB) - mu * mu;
        float rs = rsqrtf(var + GN_EPS);
        float gsc = gw[t] * rs;
        sD[128 + t] = gsc;
        sD[256 + t] = gb[t] - mu * gsc;
    }
    __syncthreads();
    // ---- P2: MFMA-1  B2T[k][(h,c)] = qinv * sum_c' pMTb[h][c][c'] * wvT[k][c'] ----
    {
        int h = wave >> 1, kh = wave & 1;
        f32x4 mac[2][4] = {};
        bf16x8 av[2];
        #pragma unroll
        for (int i = 0; i < 2; i++) av[i] = *(const bf16x8*)&pMTb[h][i * 16 + l15][lk];
        #pragma unroll
        for (int j = 0; j < 4; j++) {
            bf16x8 bv = *(const bf16x8*)&wvTb[kh * 64 + j * 16 + l15][h * 32 + lk];
            #pragma unroll
            for (int i = 0; i < 2; i++)
                mac[i][j] = __builtin_amdgcn_mfma_f32_16x16x32_bf16(av[i], bv, mac[i][j], 0, 0, 0);
        }
        #pragma unroll
        for (int i = 0; i < 2; i++)
            #pragma unroll
            for (int j = 0; j < 4; j++) {
                int k = kh * 64 + j * 16 + l15;
                int cb = h * 32 + i * 16 + (lane >> 4) * 4;
                float q0 = sD[cb], q1 = sD[cb + 1], q2 = sD[cb + 2], q3 = sD[cb + 3];
                uint2 u;
                u.x = pack2(mac[i][j][0] * q0, mac[i][j][1] * q1);
                u.y = pack2(mac[i][j][2] * q2, mac[i][j][3] * q3);
                *(uint2*)&B2T[k][cb] = u;
            }
    }
    __syncthreads();
    // ---- P3: MFMA-2  Weff[o][k] = sum_cg woutb[o][cg] * B2T[k][cg]; epilogue ----
    {
        f32x4 acc[8] = {};
        #pragma unroll
        for (int ks = 0; ks < 4; ks++) {
            bf16x8 av = *(const bf16x8*)&woutb[wave * 16 + l15][ks * 32 + lk];
            #pragma unroll
            for (int j = 0; j < 8; j++) {
                bf16x8 bv = *(const bf16x8*)&B2T[j * 16 + l15][ks * 32 + lk];
                acc[j] = __builtin_amdgcn_mfma_f32_16x16x32_bf16(av, bv, acc[j], 0, 0, 0);
            }
        }
        float gs[8], bbv[8];
        #pragma unroll
        for (int j = 0; j < 8; j++) {
            int k = j * 16 + l15;
            gs[j] = sD[128 + k];
            bbv[j] = sD[256 + k];
        }
        #pragma unroll
        for (int r = 0; r < 4; r++) {
            int o = wave * 16 + (lane >> 4) * 4 + r;
            float pb = 0.f;
            #pragma unroll
            for (int j = 0; j < 8; j++) {
                float wv = acc[j][r];
                pb += wv * bbv[j];
                WeffL[o][j * 16 + l15] = f2bf(wv * gs[j]);
            }
            pb += __shfl_xor(pb, 1);
            pb += __shfl_xor(pb, 2);
            pb += __shfl_xor(pb, 4);
            pb += __shfl_xor(pb, 8);
            if (l15 == 0) biasg[b * 128 + o] = bout[o] + pb;
        }
    }
    __syncthreads();
    // ---- P4: WeffL -> global ----
    {
        int row = t >> 2, q4 = t & 3;
        #pragma unroll
        for (int m = 0; m < 4; m++)
            *(uint4*)(weffg + (size_t)b * 16384 + row * 128 + q4 * 32 + m * 8) =
                *(uint4*)&WeffL[row][q4 * 32 + m * 8];
    }
}

// ---------------------------------------------------------------------------
// K4: y[b][o][n] = sum_k Weff'[o][k] * x[k][n] + bias'[o].  grid (16 nt, 16 b), 512 thr.
// LDS: Wfb us[128][136]@0 | Xl f32[128][68]@34816 | xT us[64][136]@69632 | sDb f32[128]@87040
__global__ __launch_bounds__(512, 1) void k_out2(const float* __restrict__ x,
                                                 float* __restrict__ ws,
                                                 float* __restrict__ y) {
    __shared__ __align__(16) char smem[87552];
    unsigned short (*Wfb)[136] = (unsigned short(*)[136])smem;
    float (*Xl)[68] = (float(*)[68])(smem + 34816);
    unsigned short (*xT)[136] = (unsigned short(*)[136])(smem + 69632);
    float* sDb = (float*)(smem + 87040);

    unsigned short* weffg = (unsigned short*)(ws + WS_WEFF);
    float* biasg = ws + WS_BIAS;

    int nt = blockIdx.x, b = blockIdx.y, t = threadIdx.x;
    int lane = t & 63, wave = t >> 6;
    int l15 = lane & 15, lk = (lane >> 4) * 8;

    // ---- P1: stage Weff', x tile, bias ----
    if (t < 128) sDb[t] = biasg[b * 128 + t];
    {
        int row = t >> 2, q4 = t & 3;
        const uint4* src = (const uint4*)(weffg + (size_t)b * 16384 + row * 128) + q4 * 4;
        #pragma unroll
        for (int m = 0; m < 4; m++) *(uint4*)&Wfb[row][q4 * 32 + m * 8] = src[m];
    }
    {
        int cx = t >> 2, qtr = t & 3;
        const float4* xsrc = (const float4*)(x + ((size_t)b * CIN + cx) * NTOK + nt * 64 + qtr * 16);
        #pragma unroll
        for (int i = 0; i < 4; i++) *(float4*)&Xl[cx][qtr * 16 + i * 4] = xsrc[i];
    }
    __syncthreads();
    // ---- P2: transpose + bf16 ----
    {
        int n = t & 63, kq = (t >> 6) * 16;
        unsigned pk[8];
        #pragma unroll
        for (int j = 0; j < 8; j++) pk[j] = pack2(Xl[kq + 2 * j][n], Xl[kq + 2 * j + 1][n]);
        *(uint4*)&xT[n][kq] = *(uint4*)pk;
        *(uint4*)(&xT[n][kq] + 8) = *(uint4*)(pk + 4);
    }
    __syncthreads();
    // ---- P3: MFMA + store ----
    int o0 = (wave >> 1) * 32, n0 = (wave & 1) * 32;
    f32x4 acc[2][2] = {};
    #pragma unroll
    for (int ks = 0; ks < 4; ks++) {
        bf16x8 av[2], bv[2];
        #pragma unroll
        for (int i = 0; i < 2; i++) av[i] = *(const bf16x8*)&Wfb[o0 + i * 16 + l15][ks * 32 + lk];
        #pragma unroll
        for (int j = 0; j < 2; j++) bv[j] = *(const bf16x8*)&xT[n0 + j * 16 + l15][ks * 32 + lk];
        #pragma unroll
        for (int i = 0; i < 2; i++)
            #pragma unroll
            for (int j = 0; j < 2; j++)
                acc[i][j] = __builtin_amdgcn_mfma_f32_16x16x32_bf16(av[i], bv[j], acc[i][j], 0, 0, 0);
    }
    #pragma unroll
    for (int i = 0; i < 2; i++)
        #pragma unroll
        for (int r = 0; r < 4; r++) {
            int o = o0 + i * 16 + (lane >> 4) * 4 + r;
            float bias = sDb[o];
            float* yp = y + ((size_t)b * CIN + o) * NTOK + nt * 64 + n0;
            #pragma unroll
            for (int j = 0; j < 2; j++) yp[j * 16 + l15] = acc[i][j][r] + bias;
        }
}

// ---------------------------------------------------------------------------
extern "C" void kernel_launch(void* const* d_in, const int* in_sizes, int n_in,
                              void* d_out, int out_size, void* d_ws, size_t ws_size,
                              hipStream_t stream) {
    const float* x = (const float*)d_in[0];
    const float* gw = (const float*)d_in[1];
    const float* gb = (const float*)d_in[2];
    const float* wqkv = (const float*)d_in[3];
    const float* wout = (const float*)d_in[4];
    const float* bout = (const float*)d_in[5];
    float* y = (float*)d_out;
    float* ws = (float*)d_ws;

    k_pre<<<dim3(256), 256, 0, stream>>>(x, wqkv, ws);
    k_qk<<<dim3(256), 512, 0, stream>>>(x, gw, gb, ws);
    k_weff<<<dim3(16), 512, 0, stream>>>(gw, gb, wout, bout, ws);
    k_out2<<<dim3(16, 16), 512, 0, stream>>>(x, ws, y);
}

// Round 8
// 92.089 us; speedup vs baseline: 1.0602x; 1.0602x over previous
//
#include <hip/hip_runtime.h>
#include <math.h>

// B=16, C=128, N=1024, HEADS=4, DIM_HEAD=32. qkv rows = 384 (q:0-127, k:128-255, v:256-383).
#define CIN 128
#define NTOK 1024
#define SCALE_Q 0.17677669529663687f /* 32^-0.5 */
#define GN_EPS 1e-5f
#define PB (CIN * NTOK) /* 131072 */

// ---- workspace layout (float units) ----
#define WS_WQKVB 0        /* bf16 [256][128] q,k weights (16384 fl) */
#define WS_WVT   16384    /* bf16 [128][128] wvT[k][c']  (8192 fl)  */
#define WS_PSTATS 24576   /* f32 [256][2]                (512 fl)   */
#define WS_QSUMG 25088    /* f32 [16][128]  atomic       (2048 fl)  */
#define WS_MG    27136    /* f32 [16][4][32][32] atomic  (16384 fl) */
// zero region = [WS_QSUMG, WS_QSUMG+18432)

typedef __bf16 bf16x8 __attribute__((ext_vector_type(8)));
typedef float f32x4 __attribute__((ext_vector_type(4)));

__device__ __forceinline__ unsigned short f2bf(float f) {
    union { float f; unsigned u; } v; v.f = f;
    unsigned r = v.u + 0x7fffu + ((v.u >> 16) & 1u);
    return (unsigned short)(r >> 16);
}
__device__ __forceinline__ unsigned pack2(float a, float b) {
    return (unsigned)f2bf(a) | ((unsigned)f2bf(b) << 16);
}

// ---------------------------------------------------------------------------
// K1: stats partials; q/k weights -> bf16; v weights -> wvT bf16; zero accums.
__global__ __launch_bounds__(256) void k_pre(const float* __restrict__ x,
                                             const float* __restrict__ wqkv,
                                             float* __restrict__ ws) {
    float* pstats = ws + WS_PSTATS;
    unsigned short* wqkvb = (unsigned short*)(ws + WS_WQKVB);
    unsigned short* wvT = (unsigned short*)(ws + WS_WVT);
    __shared__ float sD[8];
    int bid = blockIdx.x, t = threadIdx.x;
    int lane = t & 63, wave = t >> 6;
    int gid = bid * 256 + t;
    if (gid < 18432) ws[WS_QSUMG + gid] = 0.f;   // zero qsumg + Mg
    const float4* p = (const float4*)(x + (size_t)bid * 8192);
    float s = 0.f, s2 = 0.f;
    #pragma unroll
    for (int i = 0; i < 8; i++) {
        float4 v = p[t + 256 * i];
        s += v.x + v.y + v.z + v.w;
        s2 += v.x * v.x + v.y * v.y + v.z * v.z + v.w * v.w;
    }
    #pragma unroll
    for (int off = 32; off; off >>= 1) {
        s += __shfl_down(s, off);
        s2 += __shfl_down(s2, off);
    }
    if (lane == 0) { sD[wave * 2] = s; sD[wave * 2 + 1] = s2; }
    if (bid < 32) {                 // q,k rows -> bf16 row-major
        float4 v = ((const float4*)(wqkv + bid * 1024))[t];
        uint2 pk2; pk2.x = pack2(v.x, v.y); pk2.y = pack2(v.z, v.w);
        *(uint2*)(wqkvb + bid * 1024 + t * 4) = pk2;
    } else if (bid < 48) {          // v rows transposed: wvT[k][c'] = wqkv[256+c'][k]
        int g = bid - 32;
        int kk = g * 8 + (t >> 5), cq = t & 31;
        float v0 = wqkv[(256 + cq * 4 + 0) * 128 + kk];
        float v1 = wqkv[(256 + cq * 4 + 1) * 128 + kk];
        float v2 = wqkv[(256 + cq * 4 + 2) * 128 + kk];
        float v3 = wqkv[(256 + cq * 4 + 3) * 128 + kk];
        uint2 pk2; pk2.x = pack2(v0, v1); pk2.y = pack2(v2, v3);
        *(uint2*)(wvT + kk * 128 + cq * 4) = pk2;
    }
    __syncthreads();
    if (t == 0) {
        pstats[bid * 2] = sD[0] + sD[2] + sD[4] + sD[6];
        pstats[bid * 2 + 1] = sD[1] + sD[3] + sD[5] + sD[7];
    }
}

// ---------------------------------------------------------------------------
// K2: per (b, 64-token tile), 512 thr, 2 barriers. GN (regs) -> Al bf16 direct
// scatter; q/k MFMA; exp + k-softmax; qsum atomics; M-MFMA -> Mg atomics.
// LDS: Al us[64][136]@0 | Bl us[256][136]@17408 | kTl us[128][68]@87040 |
//      qTl us[128][68]@104448.  total 121856 B.
__global__ __launch_bounds__(512, 1) void k_qk(const float* __restrict__ x,
                                               const float* __restrict__ gw,
                                               const float* __restrict__ gb,
                                               float* __restrict__ ws) {
    __shared__ __align__(16) char smem[121856];
    unsigned short (*Al)[136] = (unsigned short(*)[136])smem;
    unsigned short (*Bl)[136] = (unsigned short(*)[136])(smem + 17408);
    unsigned short (*kTl)[68] = (unsigned short(*)[68])(smem + 87040);
    unsigned short (*qTl)[68] = (unsigned short(*)[68])(smem + 104448);

    unsigned short* wqkvb = (unsigned short*)(ws + WS_WQKVB);
    float* pstats = ws + WS_PSTATS;
    float* qsumg = ws + WS_QSUMG;
    float* Mg = ws + WS_MG;

    int bid = blockIdx.x, t = threadIdx.x;
    int b = bid >> 4, nt = bid & 15;
    int lane = t & 63, wave = t >> 6;
    int l15 = lane & 15, lk = (lane >> 4) * 8;
    int sel = wave >> 1, wn0 = (wave & 1) * 32;

    // ---- P0 (no barriers inside): uniform stats; weights -> Bl; x GN -> Al ----
    float mu, rsv;
    {
        float s = 0.f, s2 = 0.f;
        #pragma unroll
        for (int i = 0; i < 16; i++) {
            s += pstats[b * 32 + 2 * i];
            s2 += pstats[b * 32 + 2 * i + 1];
        }
        mu = s * (1.f / PB);
        float var = s2 * (1.f / PB) - mu * mu;
        rsv = rsqrtf(var + GN_EPS);
    }
    {   // stage q+k weights (rows 0..255)
        int row = t >> 1, hf = t & 1;
        const uint4* src = (const uint4*)(wqkvb + (size_t)row * CIN + hf * 64);
        uint4* dst = (uint4*)&Bl[row][hf * 64];
        #pragma unroll
        for (int j = 0; j < 8; j++) dst[j] = src[j];
    }
    {   // x tile: channel c, 16 tokens; GN in regs; bf16 scatter -> Al[n][c]
        int c = t & 127, seg = t >> 7;
        const float4* xsrc = (const float4*)(x + ((size_t)b * CIN + c) * NTOK + nt * 64 + seg * 16);
        float g = gw[c] * rsv, bb = gb[c] - mu * g;
        #pragma unroll
        for (int q4 = 0; q4 < 4; q4++) {
            float4 v = xsrc[q4];
            int n = seg * 16 + q4 * 4;
            Al[n + 0][c] = f2bf(v.x * g + bb);
            Al[n + 1][c] = f2bf(v.y * g + bb);
            Al[n + 2][c] = f2bf(v.z * g + bb);
            Al[n + 3][c] = f2bf(v.w * g + bb);
        }
    }
    __syncthreads();
    // ---- P1: q/k MFMA; exp; k-softmax; transposed stores; qsum atomics ----
    f32x4 acc[2][4] = {};
    #pragma unroll
    for (int ks = 0; ks < 4; ks++) {
        bf16x8 av[2], bv[4];
        #pragma unroll
        for (int i = 0; i < 2; i++) av[i] = *(const bf16x8*)&Al[wn0 + i * 16 + l15][ks * 32 + lk];
        #pragma unroll
        for (int j = 0; j < 4; j++) bv[j] = *(const bf16x8*)&Bl[sel * 64 + j * 16 + l15][ks * 32 + lk];
        #pragma unroll
        for (int i = 0; i < 2; i++)
            #pragma unroll
            for (int j = 0; j < 4; j++)
                acc[i][j] = __builtin_amdgcn_mfma_f32_16x16x32_bf16(av[i], bv[j], acc[i][j], 0, 0, 0);
    }
    float e[2][4][4];
    #pragma unroll
    for (int i = 0; i < 2; i++)
        #pragma unroll
        for (int j = 0; j < 4; j++)
            #pragma unroll
            for (int r = 0; r < 4; r++) e[i][j][r] = __expf(acc[i][j][r]);

    if (sel >= 2) {   // k rows: per-(token,head) softmax over 32 channels
        #pragma unroll
        for (int i = 0; i < 2; i++)
            #pragma unroll
            for (int r = 0; r < 4; r++) {
                float e01 = e[i][0][r] + e[i][1][r];
                float e23 = e[i][2][r] + e[i][3][r];
                #pragma unroll
                for (int m = 1; m < 16; m <<= 1) {
                    e01 += __shfl_xor(e01, m);
                    e23 += __shfl_xor(e23, m);
                }
                float i01 = 1.f / e01, i23 = 1.f / e23;
                e[i][0][r] *= i01; e[i][1][r] *= i01;
                e[i][2][r] *= i23; e[i][3][r] *= i23;
            }
        #pragma unroll
        for (int i = 0; i < 2; i++)
            #pragma unroll
            for (int j = 0; j < 4; j++) {
                int ch = (sel - 2) * 64 + j * 16 + l15;
                int tokb = wn0 + i * 16 + (lane >> 4) * 4;
                *(unsigned*)&kTl[ch][tokb] = pack2(e[i][j][0], e[i][j][1]);
                *(unsigned*)&kTl[ch][tokb + 2] = pack2(e[i][j][2], e[i][j][3]);
            }
    } else {          // q rows: transposed e^q + per-channel qsum atomics
        #pragma unroll
        for (int i = 0; i < 2; i++)
            #pragma unroll
            for (int j = 0; j < 4; j++) {
                int ch = sel * 64 + j * 16 + l15;
                int tokb = wn0 + i * 16 + (lane >> 4) * 4;
                *(unsigned*)&qTl[ch][tokb] = pack2(e[i][j][0], e[i][j][1]);
                *(unsigned*)&qTl[ch][tokb + 2] = pack2(e[i][j][2], e[i][j][3]);
            }
        #pragma unroll
        for (int j = 0; j < 4; j++) {
            float sq = 0.f;
            #pragma unroll
            for (int i = 0; i < 2; i++)
                #pragma unroll
                for (int r = 0; r < 4; r++) sq += e[i][j][r];
            sq += __shfl_xor(sq, 16);
            sq += __shfl_xor(sq, 32);
            if (lane < 16) atomicAdd(&qsumg[b * 128 + sel * 64 + j * 16 + lane], sq);
        }
    }
    __syncthreads();
    // ---- P2: M-MFMA (waves 0-3 = heads) + atomic accumulate into Mg ----
    if (wave < 4) {
        int h = wave;
        f32x4 mac[2][2] = {};
        #pragma unroll
        for (int ks = 0; ks < 2; ks++) {
            bf16x8 av[2], bv[2];
            #pragma unroll
            for (int i = 0; i < 2; i++) av[i] = *(const bf16x8*)&qTl[h * 32 + i * 16 + l15][ks * 32 + lk];
            #pragma unroll
            for (int j = 0; j < 2; j++) bv[j] = *(const bf16x8*)&kTl[h * 32 + j * 16 + l15][ks * 32 + lk];
            #pragma unroll
            for (int i = 0; i < 2; i++)
                #pragma unroll
                for (int j = 0; j < 2; j++)
                    mac[i][j] = __builtin_amdgcn_mfma_f32_16x16x32_bf16(av[i], bv[j], mac[i][j], 0, 0, 0);
        }
        // D[c][c'] = sum_n e^q[n][c] * k_sm[n][c']
        float* mb = Mg + (size_t)b * 4096 + h * 1024;
        #pragma unroll
        for (int i = 0; i < 2; i++)
            #pragma unroll
            for (int j = 0; j < 2; j++)
                #pragma unroll
                for (int r = 0; r < 4; r++)
                    atomicAdd(&mb[(i * 16 + (lane >> 4) * 4 + r) * 32 + j * 16 + l15], mac[i][j][r]);
    }
}

// ---------------------------------------------------------------------------
// K3: per (b, nt), 512 thr. Redundant per-block fold (Mg is 16KB, L2/L3-hit):
// pMTb,wvTb,woutb staged; B2T = qinv*(M x wvT); WeffL = wout x B2T;
// y = WeffL x Al^T + bout, with Al = GN'd x tile (same scatter as K2).
// LDS: Al us[64][136]@0 | pMTb us[4][32][40]@17408 | wvTb/WeffL us[128][136]@27648 |
//      woutb us[128][136]@62464 | B2T us[128][136]@97280 | biasL f32[128]@132096.
__global__ __launch_bounds__(512, 1) void k_fold_out(const float* __restrict__ x,
                                                     const float* __restrict__ gw,
                                                     const float* __restrict__ gb,
                                                     const float* __restrict__ wout,
                                                     const float* __restrict__ bout,
                                                     float* __restrict__ ws,
                                                     float* __restrict__ y) {
    __shared__ __align__(16) char smem[132608];
    unsigned short (*Al)[136] = (unsigned short(*)[136])smem;
    unsigned short (*pMTb)[32][40] = (unsigned short(*)[32][40])(smem + 17408);
    unsigned short (*wvTb)[136] = (unsigned short(*)[136])(smem + 27648);
    unsigned short (*WeffL)[136] = (unsigned short(*)[136])(smem + 27648);
    unsigned short (*woutb)[136] = (unsigned short(*)[136])(smem + 62464);
    unsigned short (*B2T)[136] = (unsigned short(*)[136])(smem + 97280);
    float* biasL = (float*)(smem + 132096);

    float* pstats = ws + WS_PSTATS;
    float* qsumg = ws + WS_QSUMG;
    float* Mg = ws + WS_MG;
    unsigned short* wvTg = (unsigned short*)(ws + WS_WVT);

    int bid = blockIdx.x, t = threadIdx.x;
    int b = bid >> 4, nt = bid & 15;
    int lane = t & 63, wave = t >> 6;
    int l15 = lane & 15, lk = (lane >> 4) * 8;

    // ---- P0: uniform stats; x GN -> Al; stage pMTb, wvTb, woutb, bias ----
    float mu, rsv;
    {
        float s = 0.f, s2 = 0.f;
        #pragma unroll
        for (int i = 0; i < 16; i++) {
            s += pstats[b * 32 + 2 * i];
            s2 += pstats[b * 32 + 2 * i + 1];
        }
        mu = s * (1.f / PB);
        float var = s2 * (1.f / PB) - mu * mu;
        rsv = rsqrtf(var + GN_EPS);
    }
    {
        int c = t & 127, seg = t >> 7;
        const float4* xsrc = (const float4*)(x + ((size_t)b * CIN + c) * NTOK + nt * 64 + seg * 16);
        float g = gw[c] * rsv, bb = gb[c] - mu * g;
        #pragma unroll
        for (int q4 = 0; q4 < 4; q4++) {
            float4 v = xsrc[q4];
            int n = seg * 16 + q4 * 4;
            Al[n + 0][c] = f2bf(v.x * g + bb);
            Al[n + 1][c] = f2bf(v.y * g + bb);
            Al[n + 2][c] = f2bf(v.z * g + bb);
            Al[n + 3][c] = f2bf(v.w * g + bb);
        }
    }
    {   // Mg -> pMTb bf16 (8 floats per thread)
        int base = t * 8;
        int h = base >> 10, idx = base & 1023, c = idx >> 5, cp0 = idx & 31;
        float4 m0 = *(const float4*)&Mg[(size_t)b * 4096 + base];
        float4 m1 = *(const float4*)&Mg[(size_t)b * 4096 + base + 4];
        uint4 u;
        u.x = pack2(m0.x, m0.y); u.y = pack2(m0.z, m0.w);
        u.z = pack2(m1.x, m1.y); u.w = pack2(m1.z, m1.w);
        *(uint4*)&pMTb[h][c][cp0] = u;
    }
    {   // wvT -> LDS
        int row = t >> 2, q4 = t & 3;
        const uint4* src = (const uint4*)(wvTg + row * 128) + q4 * 4;
        #pragma unroll
        for (int m = 0; m < 4; m++) *(uint4*)&wvTb[row][q4 * 32 + m * 8] = src[m];
    }
    {   // wout f32 -> bf16 LDS
        int row = t >> 2, q4 = t & 3;
        const float4* src = (const float4*)(wout + row * 128 + q4 * 32);
        #pragma unroll
        for (int i = 0; i < 8; i++) {
            float4 v = src[i];
            uint2 u; u.x = pack2(v.x, v.y); u.y = pack2(v.z, v.w);
            *(uint2*)&woutb[row][q4 * 32 + i * 4] = u;
        }
    }
    if (t < 128) biasL[t] = bout[t];
    __syncthreads();
    // ---- P1: B2T[k][(h,c)] = qinv[c] * sum_c' M[h][c][c'] * wvT[k][c'] ----
    {
        int h = wave >> 1, kh = wave & 1;
        f32x4 mac[2][4] = {};
        bf16x8 av[2];
        #pragma unroll
        for (int i = 0; i < 2; i++) av[i] = *(const bf16x8*)&pMTb[h][i * 16 + l15][lk];
        #pragma unroll
        for (int j = 0; j < 4; j++) {
            bf16x8 bv = *(const bf16x8*)&wvTb[kh * 64 + j * 16 + l15][h * 32 + lk];
            #pragma unroll
            for (int i = 0; i < 2; i++)
                mac[i][j] = __builtin_amdgcn_mfma_f32_16x16x32_bf16(av[i], bv, mac[i][j], 0, 0, 0);
        }
        #pragma unroll
        for (int i = 0; i < 2; i++) {
            int cb = h * 32 + i * 16 + (lane >> 4) * 4;
            float4 qs = *(const float4*)&qsumg[b * 128 + cb];
            float q0 = SCALE_Q / qs.x, q1 = SCALE_Q / qs.y;
            float q2 = SCALE_Q / qs.z, q3 = SCALE_Q / qs.w;
            #pragma unroll
            for (int j = 0; j < 4; j++) {
                int k = kh * 64 + j * 16 + l15;
                uint2 u;
                u.x = pack2(mac[i][j][0] * q0, mac[i][j][1] * q1);
                u.y = pack2(mac[i][j][2] * q2, mac[i][j][3] * q3);
                *(uint2*)&B2T[k][cb] = u;
            }
        }
    }
    __syncthreads();
    // ---- P2: WeffL[o][k] = sum_cg woutb[o][cg] * B2T[k][cg] ----
    {
        f32x4 a2[8] = {};
        #pragma unroll
        for (int ks = 0; ks < 4; ks++) {
            bf16x8 av = *(const bf16x8*)&woutb[wave * 16 + l15][ks * 32 + lk];
            #pragma unroll
            for (int j = 0; j < 8; j++) {
                bf16x8 bv = *(const bf16x8*)&B2T[j * 16 + l15][ks * 32 + lk];
                a2[j] = __builtin_amdgcn_mfma_f32_16x16x32_bf16(av, bv, a2[j], 0, 0, 0);
            }
        }
        __syncthreads();   // wvTb reads done (P1), safe to overwrite as WeffL
        #pragma unroll
        for (int j = 0; j < 8; j++)
            #pragma unroll
            for (int r = 0; r < 4; r++)
                WeffL[wave * 16 + (lane >> 4) * 4 + r][j * 16 + l15] = f2bf(a2[j][r]);
    }
    __syncthreads();
    // ---- P3: y = WeffL x Al^T + bout ----
    {
        int o0 = (wave >> 1) * 32, n0 = (wave & 1) * 32;
        f32x4 ya[2][2] = {};
        #pragma unroll
        for (int ks = 0; ks < 4; ks++) {
            bf16x8 av[2], bv[2];
            #pragma unroll
            for (int i = 0; i < 2; i++) av[i] = *(const bf16x8*)&WeffL[o0 + i * 16 + l15][ks * 32 + lk];
            #pragma unroll
            for (int j = 0; j < 2; j++) bv[j] = *(const bf16x8*)&Al[n0 + j * 16 + l15][ks * 32 + lk];
            #pragma unroll
            for (int i = 0; i < 2; i++)
                #pragma unroll
                for (int j = 0; j < 2; j++)
                    ya[i][j] = __builtin_amdgcn_mfma_f32_16x16x32_bf16(av[i], bv[j], ya[i][j], 0, 0, 0);
        }
        #pragma unroll
        for (int i = 0; i < 2; i++)
            #pragma unroll
            for (int r = 0; r < 4; r++) {
                int o = o0 + i * 16 + (lane >> 4) * 4 + r;
                float bias = biasL[o];
                float* yp = y + ((size_t)b * CIN + o) * NTOK + nt * 64 + n0;
                #pragma unroll
                for (int j = 0; j < 2; j++) yp[j * 16 + l15] = ya[i][j][r] + bias;
            }
    }
}

// ---------------------------------------------------------------------------
extern "C" void kernel_launch(void* const* d_in, const int* in_sizes, int n_in,
                              void* d_out, int out_size, void* d_ws, size_t ws_size,
                              hipStream_t stream) {
    const float* x = (const float*)d_in[0];
    const float* gw = (const float*)d_in[1];
    const float* gb = (const float*)d_in[2];
    const float* wqkv = (const float*)d_in[3];
    const float* wout = (const float*)d_in[4];
    const float* bout = (const float*)d_in[5];
    float* y = (float*)d_out;
    float* ws = (float*)d_ws;

    k_pre<<<dim3(256), 256, 0, stream>>>(x, wqkv, ws);
    k_qk<<<dim3(256), 512, 0, stream>>>(x, gw, gb, ws);
    k_fold_out<<<dim3(256), 512, 0, stream>>>(x, gw, gb, wout, bout, ws, y);
}

// Round 11
// 91.722 us; speedup vs baseline: 1.0645x; 1.0040x over previous
//
#include <hip/hip_runtime.h>
#include <math.h>

// B=16, C=128, N=1024, HEADS=4, DIM_HEAD=32. qkv rows = 384 (q:0-127, k:128-255, v:256-383).
#define CIN 128
#define NTOK 1024
#define SCALE_Q 0.17677669529663687f /* 32^-0.5 */
#define GN_EPS 1e-5f
#define PB (CIN * NTOK) /* 131072 */

// ---- workspace layout (float units) ----
#define WS_WQKVB 0        /* bf16 [256][128] q,k weights (16384 fl) */
#define WS_WVT   16384    /* bf16 [128][128] wvT[k][c']  (8192 fl)  */
#define WS_WOUTB 24576    /* bf16 [128][128] wout        (8192 fl)  */
#define WS_PSTATS 32768   /* f32 [256][2]                (512 fl)   */
#define WS_QSUMG 33280    /* f32 [16][128]  atomic       (2048 fl)  */
#define WS_MG    35328    /* f32 [16][4][32][32] atomic  (16384 fl) */
// zero region = [WS_QSUMG, WS_QSUMG+18432)

typedef __bf16 bf16x8 __attribute__((ext_vector_type(8)));
typedef float f32x4 __attribute__((ext_vector_type(4)));

__device__ __forceinline__ unsigned short f2bf(float f) {
    union { float f; unsigned u; } v; v.f = f;
    unsigned r = v.u + 0x7fffu + ((v.u >> 16) & 1u);
    return (unsigned short)(r >> 16);
}
__device__ __forceinline__ unsigned pack2(float a, float b) {
    return (unsigned)f2bf(a) | ((unsigned)f2bf(b) << 16);
}

// ---------------------------------------------------------------------------
// K1: stats partials; q/k weights -> bf16; v weights -> wvT bf16; wout -> bf16;
// zero accumulators.
__global__ __launch_bounds__(256) void k_pre(const float* __restrict__ x,
                                             const float* __restrict__ wqkv,
                                             const float* __restrict__ wout,
                                             float* __restrict__ ws) {
    float* pstats = ws + WS_PSTATS;
    unsigned short* wqkvb = (unsigned short*)(ws + WS_WQKVB);
    unsigned short* wvT = (unsigned short*)(ws + WS_WVT);
    unsigned short* woutbg = (unsigned short*)(ws + WS_WOUTB);
    __shared__ float sD[8];
    int bid = blockIdx.x, t = threadIdx.x;
    int lane = t & 63, wave = t >> 6;
    int gid = bid * 256 + t;
    if (gid < 18432) ws[WS_QSUMG + gid] = 0.f;   // zero qsumg + Mg
    const float4* p = (const float4*)(x + (size_t)bid * 8192);
    float s = 0.f, s2 = 0.f;
    #pragma unroll
    for (int i = 0; i < 8; i++) {
        float4 v = p[t + 256 * i];
        s += v.x + v.y + v.z + v.w;
        s2 += v.x * v.x + v.y * v.y + v.z * v.z + v.w * v.w;
    }
    #pragma unroll
    for (int off = 32; off; off >>= 1) {
        s += __shfl_down(s, off);
        s2 += __shfl_down(s2, off);
    }
    if (lane == 0) { sD[wave * 2] = s; sD[wave * 2 + 1] = s2; }
    if (bid < 32) {                 // q,k rows -> bf16 row-major
        float4 v = ((const float4*)(wqkv + bid * 1024))[t];
        uint2 pk2; pk2.x = pack2(v.x, v.y); pk2.y = pack2(v.z, v.w);
        *(uint2*)(wqkvb + bid * 1024 + t * 4) = pk2;
    } else if (bid < 48) {          // v rows transposed: wvT[k][c'] = wqkv[256+c'][k]
        int g = bid - 32;
        int kk = g * 8 + (t >> 5), cq = t & 31;
        float v0 = wqkv[(256 + cq * 4 + 0) * 128 + kk];
        float v1 = wqkv[(256 + cq * 4 + 1) * 128 + kk];
        float v2 = wqkv[(256 + cq * 4 + 2) * 128 + kk];
        float v3 = wqkv[(256 + cq * 4 + 3) * 128 + kk];
        uint2 pk2; pk2.x = pack2(v0, v1); pk2.y = pack2(v2, v3);
        *(uint2*)(wvT + kk * 128 + cq * 4) = pk2;
    } else if (bid == 48) {         // wout (128x128) -> bf16
        #pragma unroll
        for (int i = 0; i < 16; i++) {
            float4 v = ((const float4*)wout)[t * 16 + i];
            uint2 pk2; pk2.x = pack2(v.x, v.y); pk2.y = pack2(v.z, v.w);
            *(uint2*)(woutbg + t * 64 + i * 4) = pk2;
        }
    }
    __syncthreads();
    if (t == 0) {
        pstats[bid * 2] = sD[0] + sD[2] + sD[4] + sD[6];
        pstats[bid * 2 + 1] = sD[1] + sD[3] + sD[5] + sD[7];
    }
}

// ---------------------------------------------------------------------------
// K2: per (b, 64-token tile), 512 thr, 2 barriers. GN (regs) -> Al bf16 direct
// scatter; q/k MFMA; exp + k-softmax; qsum atomics; M-MFMA -> Mg atomics.
// LDS: Al us[64][136]@0 | Bl us[256][136]@17408 | kTl us[128][68]@87040 |
//      qTl us[128][68]@104448.  total 121856 B.
__global__ __launch_bounds__(512, 1) void k_qk(const float* __restrict__ x,
                                               const float* __restrict__ gw,
                                               const float* __restrict__ gb,
                                               float* __restrict__ ws) {
    __shared__ __align__(16) char smem[121856];
    unsigned short (*Al)[136] = (unsigned short(*)[136])smem;
    unsigned short (*Bl)[136] = (unsigned short(*)[136])(smem + 17408);
    unsigned short (*kTl)[68] = (unsigned short(*)[68])(smem + 87040);
    unsigned short (*qTl)[68] = (unsigned short(*)[68])(smem + 104448);

    unsigned short* wqkvb = (unsigned short*)(ws + WS_WQKVB);
    float* pstats = ws + WS_PSTATS;
    float* qsumg = ws + WS_QSUMG;
    float* Mg = ws + WS_MG;

    int bid = blockIdx.x, t = threadIdx.x;
    int b = bid >> 4, nt = bid & 15;
    int lane = t & 63, wave = t >> 6;
    int l15 = lane & 15, lk = (lane >> 4) * 8;
    int sel = wave >> 1, wn0 = (wave & 1) * 32;

    // ---- P0 (no barriers inside): uniform stats; weights -> Bl; x GN -> Al ----
    float mu, rsv;
    {
        float s = 0.f, s2 = 0.f;
        #pragma unroll
        for (int i = 0; i < 16; i++) {
            s += pstats[b * 32 + 2 * i];
            s2 += pstats[b * 32 + 2 * i + 1];
        }
        mu = s * (1.f / PB);
        float var = s2 * (1.f / PB) - mu * mu;
        rsv = rsqrtf(var + GN_EPS);
    }
    {   // stage q+k weights (rows 0..255)
        int row = t >> 1, hf = t & 1;
        const uint4* src = (const uint4*)(wqkvb + (size_t)row * CIN + hf * 64);
        uint4* dst = (uint4*)&Bl[row][hf * 64];
        #pragma unroll
        for (int j = 0; j < 8; j++) dst[j] = src[j];
    }
    {   // x tile: channel c, 16 tokens; GN in regs; bf16 scatter -> Al[n][c]
        int c = t & 127, seg = t >> 7;
        const float4* xsrc = (const float4*)(x + ((size_t)b * CIN + c) * NTOK + nt * 64 + seg * 16);
        float g = gw[c] * rsv, bb = gb[c] - mu * g;
        #pragma unroll
        for (int q4 = 0; q4 < 4; q4++) {
            float4 v = xsrc[q4];
            int n = seg * 16 + q4 * 4;
            Al[n + 0][c] = f2bf(v.x * g + bb);
            Al[n + 1][c] = f2bf(v.y * g + bb);
            Al[n + 2][c] = f2bf(v.z * g + bb);
            Al[n + 3][c] = f2bf(v.w * g + bb);
        }
    }
    __syncthreads();
    // ---- P1: q/k MFMA; exp; k-softmax; transposed stores; qsum atomics ----
    f32x4 acc[2][4] = {};
    #pragma unroll
    for (int ks = 0; ks < 4; ks++) {
        bf16x8 av[2], bv[4];
        #pragma unroll
        for (int i = 0; i < 2; i++) av[i] = *(const bf16x8*)&Al[wn0 + i * 16 + l15][ks * 32 + lk];
        #pragma unroll
        for (int j = 0; j < 4; j++) bv[j] = *(const bf16x8*)&Bl[sel * 64 + j * 16 + l15][ks * 32 + lk];
        #pragma unroll
        for (int i = 0; i < 2; i++)
            #pragma unroll
            for (int j = 0; j < 4; j++)
                acc[i][j] = __builtin_amdgcn_mfma_f32_16x16x32_bf16(av[i], bv[j], acc[i][j], 0, 0, 0);
    }
    float e[2][4][4];
    #pragma unroll
    for (int i = 0; i < 2; i++)
        #pragma unroll
        for (int j = 0; j < 4; j++)
            #pragma unroll
            for (int r = 0; r < 4; r++) e[i][j][r] = __expf(acc[i][j][r]);

    if (sel >= 2) {   // k rows: per-(token,head) softmax over 32 channels
        #pragma unroll
        for (int i = 0; i < 2; i++)
            #pragma unroll
            for (int r = 0; r < 4; r++) {
                float e01 = e[i][0][r] + e[i][1][r];
                float e23 = e[i][2][r] + e[i][3][r];
                #pragma unroll
                for (int m = 1; m < 16; m <<= 1) {
                    e01 += __shfl_xor(e01, m);
                    e23 += __shfl_xor(e23, m);
                }
                float i01 = 1.f / e01, i23 = 1.f / e23;
                e[i][0][r] *= i01; e[i][1][r] *= i01;
                e[i][2][r] *= i23; e[i][3][r] *= i23;
            }
        #pragma unroll
        for (int i = 0; i < 2; i++)
            #pragma unroll
            for (int j = 0; j < 4; j++) {
                int ch = (sel - 2) * 64 + j * 16 + l15;
                int tokb = wn0 + i * 16 + (lane >> 4) * 4;
                *(unsigned*)&kTl[ch][tokb] = pack2(e[i][j][0], e[i][j][1]);
                *(unsigned*)&kTl[ch][tokb + 2] = pack2(e[i][j][2], e[i][j][3]);
            }
    } else {          // q rows: transposed e^q + per-channel qsum atomics
        #pragma unroll
        for (int i = 0; i < 2; i++)
            #pragma unroll
            for (int j = 0; j < 4; j++) {
                int ch = sel * 64 + j * 16 + l15;
                int tokb = wn0 + i * 16 + (lane >> 4) * 4;
                *(unsigned*)&qTl[ch][tokb] = pack2(e[i][j][0], e[i][j][1]);
                *(unsigned*)&qTl[ch][tokb + 2] = pack2(e[i][j][2], e[i][j][3]);
            }
        #pragma unroll
        for (int j = 0; j < 4; j++) {
            float sq = 0.f;
            #pragma unroll
            for (int i = 0; i < 2; i++)
                #pragma unroll
                for (int r = 0; r < 4; r++) sq += e[i][j][r];
            sq += __shfl_xor(sq, 16);
            sq += __shfl_xor(sq, 32);
            if (lane < 16) atomicAdd(&qsumg[b * 128 + sel * 64 + j * 16 + lane], sq);
        }
    }
    __syncthreads();
    // ---- P2: M-MFMA (waves 0-3 = heads) + atomic accumulate into Mg ----
    // D[c][c'] = sum_n e^q[n][c] * k_sm[n][c']
    if (wave < 4) {
        int h = wave;
        f32x4 mac[2][2] = {};
        #pragma unroll
        for (int ks = 0; ks < 2; ks++) {
            bf16x8 av[2], bv[2];
            #pragma unroll
            for (int i = 0; i < 2; i++) av[i] = *(const bf16x8*)&qTl[h * 32 + i * 16 + l15][ks * 32 + lk];
            #pragma unroll
            for (int j = 0; j < 2; j++) bv[j] = *(const bf16x8*)&kTl[h * 32 + j * 16 + l15][ks * 32 + lk];
            #pragma unroll
            for (int i = 0; i < 2; i++)
                #pragma unroll
                for (int j = 0; j < 2; j++)
                    mac[i][j] = __builtin_amdgcn_mfma_f32_16x16x32_bf16(av[i], bv[j], mac[i][j], 0, 0, 0);
        }
        float* mb = Mg + (size_t)b * 4096 + h * 1024;
        #pragma unroll
        for (int i = 0; i < 2; i++)
            #pragma unroll
            for (int j = 0; j < 2; j++)
                #pragma unroll
                for (int r = 0; r < 4; r++)
                    atomicAdd(&mb[(i * 16 + (lane >> 4) * 4 + r) * 32 + j * 16 + l15], mac[i][j][r]);
    }
}

// ---------------------------------------------------------------------------
// K3: per (b, nt), 512 thr. Redundant per-block fold (Mg is 16KB, L2/L3-hit):
// pMTb,wvTb,wo_l staged; B2T = qinv*(M x wvT); WeffL = wout x B2T;
// y = WeffL x Al^T + bout, with Al = GN'd x tile (same scatter as K2).
// LDS: Al us[64][136]@0 | pMTb us[4][32][40]@17408 | wvTb/WeffL us[128][136]@27648 |
//      wo_l us[128][136]@62464 | B2T us[128][136]@97280 | biasL f32[128]@132096.
__global__ __launch_bounds__(512, 1) void k_fold_out(const float* __restrict__ x,
                                                     const float* __restrict__ gw,
                                                     const float* __restrict__ gb,
                                                     const float* __restrict__ bout,
                                                     float* __restrict__ ws,
                                                     float* __restrict__ y) {
    __shared__ __align__(16) char smem[132608];
    unsigned short (*Al)[136] = (unsigned short(*)[136])smem;
    unsigned short (*pMTb)[32][40] = (unsigned short(*)[32][40])(smem + 17408);
    unsigned short (*wvTb)[136] = (unsigned short(*)[136])(smem + 27648);
    unsigned short (*WeffL)[136] = (unsigned short(*)[136])(smem + 27648);
    unsigned short (*wo_l)[136] = (unsigned short(*)[136])(smem + 62464);
    unsigned short (*B2T)[136] = (unsigned short(*)[136])(smem + 97280);
    float* biasL = (float*)(smem + 132096);

    float* pstats = ws + WS_PSTATS;
    float* qsumg = ws + WS_QSUMG;
    float* Mg = ws + WS_MG;
    unsigned short* wvTg = (unsigned short*)(ws + WS_WVT);
    unsigned short* woutbg = (unsigned short*)(ws + WS_WOUTB);

    int bid = blockIdx.x, t = threadIdx.x;
    int b = bid >> 4, nt = bid & 15;
    int lane = t & 63, wave = t >> 6;
    int l15 = lane & 15, lk = (lane >> 4) * 8;

    // ---- P0: uniform stats; x GN -> Al; stage pMTb, wvTb, wo_l, bias ----
    float mu, rsv;
    {
        float s = 0.f, s2 = 0.f;
        #pragma unroll
        for (int i = 0; i < 16; i++) {
            s += pstats[b * 32 + 2 * i];
            s2 += pstats[b * 32 + 2 * i + 1];
        }
        mu = s * (1.f / PB);
        float var = s2 * (1.f / PB) - mu * mu;
        rsv = rsqrtf(var + GN_EPS);
    }
    {
        int c = t & 127, seg = t >> 7;
        const float4* xsrc = (const float4*)(x + ((size_t)b * CIN + c) * NTOK + nt * 64 + seg * 16);
        float g = gw[c] * rsv, bb = gb[c] - mu * g;
        #pragma unroll
        for (int q4 = 0; q4 < 4; q4++) {
            float4 v = xsrc[q4];
            int n = seg * 16 + q4 * 4;
            Al[n + 0][c] = f2bf(v.x * g + bb);
            Al[n + 1][c] = f2bf(v.y * g + bb);
            Al[n + 2][c] = f2bf(v.z * g + bb);
            Al[n + 3][c] = f2bf(v.w * g + bb);
        }
    }
    {   // Mg -> pMTb bf16 (8 floats per thread)
        int base = t * 8;
        int h = base >> 10, idx = base & 1023, c = idx >> 5, cp0 = idx & 31;
        float4 m0 = *(const float4*)&Mg[(size_t)b * 4096 + base];
        float4 m1 = *(const float4*)&Mg[(size_t)b * 4096 + base + 4];
        uint4 u;
        u.x = pack2(m0.x, m0.y); u.y = pack2(m0.z, m0.w);
        u.z = pack2(m1.x, m1.y); u.w = pack2(m1.z, m1.w);
        *(uint4*)&pMTb[h][c][cp0] = u;
    }
    {   // wvT -> LDS
        int row = t >> 2, q4 = t & 3;
        const uint4* src = (const uint4*)(wvTg + row * 128) + q4 * 4;
        #pragma unroll
        for (int m = 0; m < 4; m++) *(uint4*)&wvTb[row][q4 * 32 + m * 8] = src[m];
    }
    {   // woutb (pre-converted bf16) -> LDS
        int row = t >> 2, q4 = t & 3;
        const uint4* src = (const uint4*)(woutbg + (size_t)row * CIN + q4 * 32);
        #pragma unroll
        for (int m = 0; m < 4; m++) *(uint4*)&wo_l[row][q4 * 32 + m * 8] = src[m];
    }
    if (t < 128) biasL[t] = bout[t];
    __syncthreads();
    // ---- P1: B2T[k][(h,c)] = qinv[c] * sum_c' M[h][c][c'] * wvT[k][c'] ----
    {
        int h = wave >> 1, kh = wave & 1;
        f32x4 mac[2][4] = {};
        bf16x8 av[2];
        #pragma unroll
        for (int i = 0; i < 2; i++) av[i] = *(const bf16x8*)&pMTb[h][i * 16 + l15][lk];
        #pragma unroll
        for (int j = 0; j < 4; j++) {
            bf16x8 bv = *(const bf16x8*)&wvTb[kh * 64 + j * 16 + l15][h * 32 + lk];
            #pragma unroll
            for (int i = 0; i < 2; i++)
                mac[i][j] = __builtin_amdgcn_mfma_f32_16x16x32_bf16(av[i], bv, mac[i][j], 0, 0, 0);
        }
        #pragma unroll
        for (int i = 0; i < 2; i++) {
            int cb = h * 32 + i * 16 + (lane >> 4) * 4;
            float4 qs = *(const float4*)&qsumg[b * 128 + cb];
            float q0 = SCALE_Q / qs.x, q1 = SCALE_Q / qs.y;
            float q2 = SCALE_Q / qs.z, q3 = SCALE_Q / qs.w;
            #pragma unroll
            for (int j = 0; j < 4; j++) {
                int k = kh * 64 + j * 16 + l15;
                uint2 u;
                u.x = pack2(mac[i][j][0] * q0, mac[i][j][1] * q1);
                u.y = pack2(mac[i][j][2] * q2, mac[i][j][3] * q3);
                *(uint2*)&B2T[k][cb] = u;
            }
        }
    }
    __syncthreads();
    // ---- P2: WeffL[o][k] = sum_cg wo_l[o][cg] * B2T[k][cg] ----
    {
        f32x4 a2[8] = {};
        #pragma unroll
        for (int ks = 0; ks < 4; ks++) {
            bf16x8 av = *(const bf16x8*)&wo_l[wave * 16 + l15][ks * 32 + lk];
            #pragma unroll
            for (int j = 0; j < 8; j++) {
                bf16x8 bv = *(const bf16x8*)&B2T[j * 16 + l15][ks * 32 + lk];
                a2[j] = __builtin_amdgcn_mfma_f32_16x16x32_bf16(av, bv, a2[j], 0, 0, 0);
            }
        }
        __syncthreads();   // wvTb reads done (P1), safe to overwrite as WeffL
        #pragma unroll
        for (int j = 0; j < 8; j++)
            #pragma unroll
            for (int r = 0; r < 4; r++)
                WeffL[wave * 16 + (lane >> 4) * 4 + r][j * 16 + l15] = f2bf(a2[j][r]);
    }
    __syncthreads();
    // ---- P3: y = WeffL x Al^T + bout ----
    {
        int o0 = (wave >> 1) * 32, n0 = (wave & 1) * 32;
        f32x4 ya[2][2] = {};
        #pragma unroll
        for (int ks = 0; ks < 4; ks++) {
            bf16x8 av[2], bv[2];
            #pragma unroll
            for (int i = 0; i < 2; i++) av[i] = *(const bf16x8*)&WeffL[o0 + i * 16 + l15][ks * 32 + lk];
            #pragma unroll
            for (int j = 0; j < 2; j++) bv[j] = *(const bf16x8*)&Al[n0 + j * 16 + l15][ks * 32 + lk];
            #pragma unroll
            for (int i = 0; i < 2; i++)
                #pragma unroll
                for (int j = 0; j < 2; j++)
                    ya[i][j] = __builtin_amdgcn_mfma_f32_16x16x32_bf16(av[i], bv[j], ya[i][j], 0, 0, 0);
        }
        #pragma unroll
        for (int i = 0; i < 2; i++)
            #pragma unroll
            for (int r = 0; r < 4; r++) {
                int o = o0 + i * 16 + (lane >> 4) * 4 + r;
                float bias = biasL[o];
                float* yp = y + ((size_t)b * CIN + o) * NTOK + nt * 64 + n0;
                #pragma unroll
                for (int j = 0; j < 2; j++) yp[j * 16 + l15] = ya[i][j][r] + bias;
            }
    }
}

// ---------------------------------------------------------------------------
extern "C" void kernel_launch(void* const* d_in, const int* in_sizes, int n_in,
                              void* d_out, int out_size, void* d_ws, size_t ws_size,
                              hipStream_t stream) {
    const float* x = (const float*)d_in[0];
    const float* gw = (const float*)d_in[1];
    const float* gb = (const float*)d_in[2];
    const float* wqkv = (const float*)d_in[3];
    const float* wout = (const float*)d_in[4];
    const float* bout = (const float*)d_in[5];
    float* y = (float*)d_out;
    float* ws = (float*)d_ws;

    k_pre<<<dim3(256), 256, 0, stream>>>(x, wqkv, wout, ws);
    k_qk<<<dim3(256), 512, 0, stream>>>(x, gw, gb, ws);
    k_fold_out<<<dim3(256), 512, 0, stream>>>(x, gw, gb, bout, ws, y);
}